// Round 1
// baseline (163.809 us; speedup 1.0000x reference)
//
#include <hip/hip_runtime.h>
#include <hip/hip_bf16.h>
#include <math.h>

constexpr int N = 16384, D = 256, C = 10000;
constexpr float S = 30.0f, MARGIN = 0.4f;
constexpr int BM = 128, BN = 128, BK = 32;
constexpr int CP = ((C + BN - 1) / BN) * BN; // 10112

using bf16 = __hip_bfloat16;
typedef __attribute__((ext_vector_type(8))) short short8;
typedef __attribute__((ext_vector_type(4))) float f32x4;

// ---------------- prep: normalize x -> bf16, tgt in f32, zero rowsum ----------------
__global__ __launch_bounds__(256) void prep_x(const float* __restrict__ x,
                                              const int* __restrict__ labels,
                                              const float* __restrict__ W,
                                              bf16* __restrict__ xn,
                                              float* __restrict__ tgt,
                                              float* __restrict__ rowsum) {
    const int row = blockIdx.x;
    const int d = threadIdx.x;           // D == 256 == blockDim.x
    const int lane = threadIdx.x & 63, w = threadIdx.x >> 6;
    __shared__ float s4[4];

    float v = x[row * D + d];
    float sq = v * v;
    #pragma unroll
    for (int off = 1; off < 64; off <<= 1) sq += __shfl_xor(sq, off);
    if (lane == 0) s4[w] = sq;
    __syncthreads();
    float nrm2 = s4[0] + s4[1] + s4[2] + s4[3];
    float rinv = rsqrtf(nrm2);
    float xv = v * rinv;
    xn[row * D + d] = __float2bfloat16(xv);

    const int lab = labels[row];
    float t = xv * W[lab * D + d];
    #pragma unroll
    for (int off = 1; off < 64; off <<= 1) t += __shfl_xor(t, off);
    __syncthreads();                      // everyone done reading s4
    if (lane == 0) s4[w] = t;
    __syncthreads();
    if (threadIdx.x == 0) {
        tgt[row] = s4[0] + s4[1] + s4[2] + s4[3];
        rowsum[row] = 0.0f;
    }
}

// ---------------- prep: W f32 -> bf16, zero-pad rows [C, CP) ----------------
__global__ __launch_bounds__(256) void prep_w(const float* __restrict__ W,
                                              bf16* __restrict__ Wb) {
    int i = blockIdx.x * 256 + threadIdx.x;   // over CP*D
    int r = i >> 8;                            // D == 256
    Wb[i] = __float2bfloat16((r < C) ? W[i] : 0.0f);
}

// ---------------- main GEMM + exp + row-sum ----------------
__global__ __launch_bounds__(256) void gemm_exp(const bf16* __restrict__ A,   // xn [N][D]
                                                const bf16* __restrict__ B,   // Wb [CP][D]
                                                float* __restrict__ rowsum) {
    __shared__ __align__(16) bf16 As[BM * BK];   // [128][32] row-major, 8 KB
    __shared__ __align__(16) bf16 Bs[BN * BK];   // [128][32] row-major, 8 KB

    const int tile_r = blockIdx.x * BM;
    const int tile_c = blockIdx.y * BN;
    const int t = threadIdx.x;
    const int lane = t & 63, w = t >> 6;
    const int wm = w >> 1, wn = w & 1;      // 2x2 wave grid, each wave 64x64

    f32x4 acc[4][4] = {};

    for (int k0 = 0; k0 < D; k0 += BK) {
        // stage A and B tiles via global_load_lds (wave-uniform LDS base + lane*16)
        #pragma unroll
        for (int c = 0; c < 2; ++c) {
            int i = c * 256 + w * 64 + lane;
            int rr = i >> 2, kq = i & 3;
            const bf16* ga = A + (tile_r + rr) * D + k0 + kq * 8;
            const bf16* gb = B + (tile_c + rr) * D + k0 + kq * 8;
            __builtin_amdgcn_global_load_lds(
                (const __attribute__((address_space(1))) void*)ga,
                (__attribute__((address_space(3))) void*)((char*)As + c * 4096 + w * 1024),
                16, 0, 0);
            __builtin_amdgcn_global_load_lds(
                (const __attribute__((address_space(1))) void*)gb,
                (__attribute__((address_space(3))) void*)((char*)Bs + c * 4096 + w * 1024),
                16, 0, 0);
        }
        __syncthreads();

        short8 af[4], bfr[4];
        #pragma unroll
        for (int m = 0; m < 4; ++m)
            af[m] = *(const short8*)(As + (wm * 64 + m * 16 + (lane & 15)) * BK + (lane >> 4) * 8);
        #pragma unroll
        for (int n = 0; n < 4; ++n)
            bfr[n] = *(const short8*)(Bs + (wn * 64 + n * 16 + (lane & 15)) * BK + (lane >> 4) * 8);

        #pragma unroll
        for (int m = 0; m < 4; ++m)
            #pragma unroll
            for (int n = 0; n < 4; ++n)
                acc[m][n] = __builtin_amdgcn_mfma_f32_16x16x32_bf16(af[m], bfr[n], acc[m][n], 0, 0, 0);
        __syncthreads();
    }

    // epilogue: exp(S*wf), mask padded cols, reduce over this wave's 64 cols, atomic per row
    #pragma unroll
    for (int m = 0; m < 4; ++m) {
        float rs[4] = {0.f, 0.f, 0.f, 0.f};
        #pragma unroll
        for (int n = 0; n < 4; ++n) {
            int gcol = tile_c + wn * 64 + n * 16 + (lane & 15);
            bool ok = (gcol < C);
            #pragma unroll
            for (int r = 0; r < 4; ++r) {
                float e = ok ? __expf(S * acc[m][n][r]) : 0.0f;
                rs[r] += e;
            }
        }
        #pragma unroll
        for (int r = 0; r < 4; ++r) {
            float v = rs[r];
            v += __shfl_xor(v, 1);
            v += __shfl_xor(v, 2);
            v += __shfl_xor(v, 4);
            v += __shfl_xor(v, 8);
            if ((lane & 15) == 0) {
                int grow = tile_r + wm * 64 + m * 16 + (lane >> 4) * 4 + r;
                atomicAdd(&rowsum[grow], v);
            }
        }
    }
}

// ---------------- loss reduction ----------------
__global__ __launch_bounds__(256) void loss_part(const float* __restrict__ tgt,
                                                 const float* __restrict__ rowsum,
                                                 float* __restrict__ partial) {
    int i = blockIdx.x * 256 + threadIdx.x;
    float tg = tgt[i];
    float num = S * (tg - MARGIN);
    float den = __expf(num) + rowsum[i] - __expf(S * tg);
    float L = num - logf(den);

    float v = L;
    #pragma unroll
    for (int off = 1; off < 64; off <<= 1) v += __shfl_xor(v, off);
    __shared__ float s4[4];
    int lane = threadIdx.x & 63, w = threadIdx.x >> 6;
    if (lane == 0) s4[w] = v;
    __syncthreads();
    if (threadIdx.x == 0) partial[blockIdx.x] = s4[0] + s4[1] + s4[2] + s4[3];
}

__global__ void loss_final(const float* __restrict__ partial, float* __restrict__ out) {
    float v = partial[threadIdx.x];   // 64 threads, 64 partials
    #pragma unroll
    for (int off = 1; off < 64; off <<= 1) v += __shfl_xor(v, off);
    if (threadIdx.x == 0) out[0] = -v / (float)N;
}

// ---------------- launch ----------------
extern "C" void kernel_launch(void* const* d_in, const int* in_sizes, int n_in,
                              void* d_out, int out_size, void* d_ws, size_t ws_size,
                              hipStream_t stream) {
    const float* x = (const float*)d_in[0];
    const int* labels = (const int*)d_in[1];
    const float* W = (const float*)d_in[2];

    char* ws = (char*)d_ws;
    bf16* xn      = (bf16*)(ws);                               // N*D*2      = 8,388,608
    bf16* Wb      = (bf16*)(ws + 8388608);                     // CP*D*2     = 5,177,344
    float* tgt    = (float*)(ws + 13565952);                   // N*4
    float* rowsum = (float*)(ws + 13631488);                   // N*4
    float* partial= (float*)(ws + 13697024);                   // 64*4
    float* out = (float*)d_out;

    prep_x<<<N, 256, 0, stream>>>(x, labels, W, xn, tgt, rowsum);
    prep_w<<<(CP * D) / 256, 256, 0, stream>>>(W, Wb);

    dim3 grid(N / BM, CP / BN);
    gemm_exp<<<grid, 256, 0, stream>>>(xn, Wb, rowsum);

    loss_part<<<N / 256, 256, 0, stream>>>(tgt, rowsum, partial);
    loss_final<<<1, 64, 0, stream>>>(partial, out);
}

// Round 2
// 161.352 us; speedup vs baseline: 1.0152x; 1.0152x over previous
//
#include <hip/hip_runtime.h>
#include <hip/hip_bf16.h>
#include <math.h>

constexpr int N = 16384, D = 256, C = 10000;
constexpr float S = 30.0f, MARGIN = 0.4f;
constexpr int BM = 128, BN = 128, BK = 64;
constexpr int CP = ((C + BN - 1) / BN) * BN; // 10112
constexpr float S_LOG2E = 43.2808512266689f; // S * log2(e)

using bf16 = __hip_bfloat16;
typedef __attribute__((ext_vector_type(8))) short short8;
typedef __attribute__((ext_vector_type(4))) float f32x4;

// ---------------- prep: normalize x -> bf16 (pre-scaled by S*log2e), tgt f32, zero rowsum ----------------
__global__ __launch_bounds__(256) void prep_x(const float* __restrict__ x,
                                              const int* __restrict__ labels,
                                              const float* __restrict__ W,
                                              bf16* __restrict__ xn,
                                              float* __restrict__ tgt,
                                              float* __restrict__ rowsum) {
    const int row = blockIdx.x;
    const int d = threadIdx.x;           // D == 256 == blockDim.x
    const int lane = threadIdx.x & 63, w = threadIdx.x >> 6;
    __shared__ float s4[4];

    float v = x[row * D + d];
    float sq = v * v;
    #pragma unroll
    for (int off = 1; off < 64; off <<= 1) sq += __shfl_xor(sq, off);
    if (lane == 0) s4[w] = sq;
    __syncthreads();
    float nrm2 = s4[0] + s4[1] + s4[2] + s4[3];
    float rinv = rsqrtf(nrm2);
    float xv = v * rinv;
    // pre-scale so GEMM accumulator IS the exp2 argument: exp(S*wf) = exp2(acc)
    xn[row * D + d] = __float2bfloat16(xv * S_LOG2E);

    const int lab = labels[row];
    float t = xv * W[lab * D + d];       // tgt in f32, UNscaled
    #pragma unroll
    for (int off = 1; off < 64; off <<= 1) t += __shfl_xor(t, off);
    __syncthreads();                      // everyone done reading s4
    if (lane == 0) s4[w] = t;
    __syncthreads();
    if (threadIdx.x == 0) {
        tgt[row] = s4[0] + s4[1] + s4[2] + s4[3];
        rowsum[row] = 0.0f;
    }
}

// ---------------- prep: W f32 -> bf16, zero-pad rows [C, CP) ----------------
__global__ __launch_bounds__(256) void prep_w(const float* __restrict__ W,
                                              bf16* __restrict__ Wb) {
    int i = blockIdx.x * 256 + threadIdx.x;   // over CP*D
    int r = i >> 8;                            // D == 256
    Wb[i] = __float2bfloat16((r < C) ? W[i] : 0.0f);
}

// ---------------- main GEMM + exp2 + row-sum ----------------
// LDS tiles [128][64] bf16, XOR-swizzled: content at (row, slot s) holds
// global (row, s ^ (row&7)) where slot = 16B granule (8 bf16). Staged via
// global_load_lds with LINEAR dest + pre-swizzled per-lane SOURCE (rule 21).
__global__ __launch_bounds__(256) void gemm_exp(const bf16* __restrict__ A,   // xn [N][D]
                                                const bf16* __restrict__ B,   // Wb [CP][D]
                                                float* __restrict__ rowsum) {
    __shared__ __align__(16) bf16 As[BM * BK];   // 16 KB
    __shared__ __align__(16) bf16 Bs[BN * BK];   // 16 KB

    const int tile_r = blockIdx.x * BM;
    const int tile_c = blockIdx.y * BN;
    const int t = threadIdx.x;
    const int lane = t & 63, w = t >> 6;
    const int wm = w >> 1, wn = w & 1;      // 2x2 wave grid, each wave 64x64

    f32x4 acc[4][4] = {};

    // staging geometry: 1 KB chunk = 8 rows x 128 B; lane l covers row l>>3, slot l&7
    const int srow  = lane >> 3;             // row within chunk (== row&7)
    const int sslot = (lane & 7) ^ srow;     // pre-swizzled source slot

    for (int k0 = 0; k0 < D; k0 += BK) {
        #pragma unroll
        for (int q = 0; q < 4; ++q) {
            int c = w * 4 + q;                // chunk 0..15 (wave-uniform)
            int rloc = c * 8 + srow;
            const bf16* ga = A + (size_t)(tile_r + rloc) * D + k0 + sslot * 8;
            const bf16* gb = B + (size_t)(tile_c + rloc) * D + k0 + sslot * 8;
            __builtin_amdgcn_global_load_lds(
                (const __attribute__((address_space(1))) void*)ga,
                (__attribute__((address_space(3))) void*)(As + c * 512),
                16, 0, 0);
            __builtin_amdgcn_global_load_lds(
                (const __attribute__((address_space(1))) void*)gb,
                (__attribute__((address_space(3))) void*)(Bs + c * 512),
                16, 0, 0);
        }
        __syncthreads();   // drains vmcnt(0) -> staged data visible

        #pragma unroll
        for (int kk = 0; kk < 2; ++kk) {
            short8 af[4], bfr[4];
            #pragma unroll
            for (int m = 0; m < 4; ++m) {
                int row = wm * 64 + m * 16 + (lane & 15);
                int slot = (kk * 4 + (lane >> 4)) ^ (lane & 7);  // row&7 == lane&7
                af[m] = *(const short8*)(As + row * 64 + slot * 8);
            }
            #pragma unroll
            for (int n = 0; n < 4; ++n) {
                int row = wn * 64 + n * 16 + (lane & 15);
                int slot = (kk * 4 + (lane >> 4)) ^ (lane & 7);
                bfr[n] = *(const short8*)(Bs + row * 64 + slot * 8);
            }
            #pragma unroll
            for (int m = 0; m < 4; ++m)
                #pragma unroll
                for (int n = 0; n < 4; ++n)
                    acc[m][n] = __builtin_amdgcn_mfma_f32_16x16x32_bf16(af[m], bfr[n], acc[m][n], 0, 0, 0);
        }
        if (k0 + BK < D) __syncthreads();  // all reads done before next overwrite
    }

    // epilogue: exp2(acc) (acc pre-scaled by S*log2e), mask padded cols,
    // reduce over wave's 16 col-lanes, one atomic per (row) per wave
    #pragma unroll
    for (int m = 0; m < 4; ++m) {
        float rs[4] = {0.f, 0.f, 0.f, 0.f};
        #pragma unroll
        for (int n = 0; n < 4; ++n) {
            int gcol = tile_c + wn * 64 + n * 16 + (lane & 15);
            bool ok = (gcol < C);
            #pragma unroll
            for (int r = 0; r < 4; ++r) {
                float e = ok ? __builtin_amdgcn_exp2f(acc[m][n][r]) : 0.0f;
                rs[r] += e;
            }
        }
        #pragma unroll
        for (int r = 0; r < 4; ++r) {
            float v = rs[r];
            v += __shfl_xor(v, 1);
            v += __shfl_xor(v, 2);
            v += __shfl_xor(v, 4);
            v += __shfl_xor(v, 8);
            if ((lane & 15) == 0) {
                int grow = tile_r + wm * 64 + m * 16 + (lane >> 4) * 4 + r;
                atomicAdd(&rowsum[grow], v);
            }
        }
    }
}

// ---------------- loss reduction ----------------
__global__ __launch_bounds__(256) void loss_part(const float* __restrict__ tgt,
                                                 const float* __restrict__ rowsum,
                                                 float* __restrict__ partial) {
    int i = blockIdx.x * 256 + threadIdx.x;
    float tg = tgt[i];
    float num = S * (tg - MARGIN);
    float den = __expf(num) + rowsum[i] - __expf(S * tg);
    float L = num - logf(den);

    float v = L;
    #pragma unroll
    for (int off = 1; off < 64; off <<= 1) v += __shfl_xor(v, off);
    __shared__ float s4[4];
    int lane = threadIdx.x & 63, w = threadIdx.x >> 6;
    if (lane == 0) s4[w] = v;
    __syncthreads();
    if (threadIdx.x == 0) partial[blockIdx.x] = s4[0] + s4[1] + s4[2] + s4[3];
}

__global__ void loss_final(const float* __restrict__ partial, float* __restrict__ out) {
    float v = partial[threadIdx.x];   // 64 threads, 64 partials
    #pragma unroll
    for (int off = 1; off < 64; off <<= 1) v += __shfl_xor(v, off);
    if (threadIdx.x == 0) out[0] = -v / (float)N;
}

// ---------------- launch ----------------
extern "C" void kernel_launch(void* const* d_in, const int* in_sizes, int n_in,
                              void* d_out, int out_size, void* d_ws, size_t ws_size,
                              hipStream_t stream) {
    const float* x = (const float*)d_in[0];
    const int* labels = (const int*)d_in[1];
    const float* W = (const float*)d_in[2];

    char* ws = (char*)d_ws;
    bf16* xn      = (bf16*)(ws);                               // N*D*2      = 8,388,608
    bf16* Wb      = (bf16*)(ws + 8388608);                     // CP*D*2     = 5,177,344
    float* tgt    = (float*)(ws + 13565952);                   // N*4
    float* rowsum = (float*)(ws + 13631488);                   // N*4
    float* partial= (float*)(ws + 13697024);                   // 64*4
    float* out = (float*)d_out;

    prep_x<<<N, 256, 0, stream>>>(x, labels, W, xn, tgt, rowsum);
    prep_w<<<(CP * D) / 256, 256, 0, stream>>>(W, Wb);

    dim3 grid(N / BM, CP / BN);
    gemm_exp<<<grid, 256, 0, stream>>>(xn, Wb, rowsum);

    loss_part<<<N / 256, 256, 0, stream>>>(tgt, rowsum, partial);
    loss_final<<<1, 64, 0, stream>>>(partial, out);
}